// Round 12
// baseline (6921.355 us; speedup 1.0000x reference)
//
#include <hip/hip_runtime.h>
#include <hip/hip_bf16.h>

#define DI 12
#define DH 512
#define DT 256
#define DB 256
#define SCOPE __HIP_MEMORY_SCOPE_AGENT

typedef float f32x4 __attribute__((ext_vector_type(4)));
typedef __bf16 bf16x8 __attribute__((ext_vector_type(8)));

__device__ __forceinline__ float sigm(float x) { return 1.f / (1.f + __expf(-x)); }
__device__ __forceinline__ float tanh_f(float x) {
    float xc = fminf(fmaxf(x, -15.f), 15.f);
    float e = __expf(-2.f * xc);
    return (1.f - e) / (1.f + e);
}
__device__ __forceinline__ float lrelu(float x) { return x > 0.f ? x : 0.01f * x; }
__device__ __forceinline__ unsigned short f2bf(float f) {
    return __builtin_bit_cast(unsigned short, (__bf16)f);
}

// Parallel h staging: issue all L3 loads first (independent), then LDS-write.
__device__ __forceinline__ void stage_h(unsigned short* hbuf, const unsigned long long* src2, int tid) {
    unsigned long long tmp[11];
    #pragma unroll
    for (int j = 0; j < 11; ++j) {
        int i = tid + j * 384;
        if (i < 4096) tmp[j] = __hip_atomic_load(src2 + i, __ATOMIC_RELAXED, SCOPE);
    }
    #pragma unroll
    for (int j = 0; j < 11; ++j) {
        int i = tid + j * 384;
        if (i < 4096) {
            int row = i >> 7, dq = i & 127;
            unsigned off = (unsigned)row * 1024u + (((unsigned)(dq * 8)) ^ ((unsigned)((row & 7) << 4)));
            *(unsigned long long*)((char*)hbuf + off) = tmp[j];
        }
    }
}

// Poller: one wave reads all 64 per-g2-wave flags of its group (one coalesced load/iter).
__device__ __forceinline__ void poll64(const unsigned* fl, int lane, unsigned gen) {
    while (true) {
        unsigned v = __hip_atomic_load(fl + lane, __ATOMIC_RELAXED, SCOPE);
        if (__all((int)(v >= gen))) break;
        __builtin_amdgcn_s_sleep(1);
    }
    __builtin_amdgcn_fence(__ATOMIC_ACQUIRE, "agent");
}

__device__ __forceinline__ f32x4 mfma_hbuf(const unsigned short* hbuf, const bf16x8* bw,
                                           int arow, int lk) {
    f32x4 acc = {0.f, 0.f, 0.f, 0.f};
    const unsigned rbase = (unsigned)arow * 1024u;
    const unsigned swz = (unsigned)((arow & 7) << 4);
    const char* hb = (const char*)hbuf;
    #pragma unroll
    for (int kk = 0; kk < 16; ++kk) {
        unsigned off = rbase + (((unsigned)(kk * 64 + lk * 16)) ^ swz);
        bf16x8 a = *(const bf16x8*)(hb + off);
        acc = __builtin_amdgcn_mfma_f32_16x16x32_bf16(a, bw[kk], acc, 0, 0, 0);
    }
    return acc;
}

// ---------------- init: zero generation flags (8 groups x 64 flags each, enc+dec) ----------------
__global__ void init_kernel(unsigned* flE, unsigned* flD) {
    int i = blockIdx.x * 256 + threadIdx.x;   // 4 blocks x 256
    if (i < 512) flE[i] = 0u;
    else flD[i - 512] = 0u;
}

// ---------------- prep: W2 = w_ih_d @ fc4_w (bf16), b2 = b_ih_d + w_ih_d@fc4_b, fc4 -> bf16 ----
__global__ void prep_kernel(const float* __restrict__ w_ih_d, const float* __restrict__ fc4_w,
                            const float* __restrict__ b_ih_d, const float* __restrict__ fc4_b,
                            unsigned short* __restrict__ W2bf, float* __restrict__ b2,
                            unsigned short* __restrict__ fc4bf)
{
    const int r = blockIdx.x, tid = threadIdx.x;   // 1552 blocks x 128 threads
    if (r < 3 * DH) {
        float wr[DI];
        #pragma unroll
        for (int k = 0; k < DI; ++k) wr[k] = w_ih_d[r * DI + k];
        int c0 = tid * 4;
        #pragma unroll
        for (int q = 0; q < 4; ++q) {
            int c = c0 + q;
            float a = 0.f;
            #pragma unroll
            for (int k = 0; k < DI; ++k) a += wr[k] * fc4_w[k * DH + c];
            W2bf[(size_t)r * DH + c] = f2bf(a);
        }
        if (tid == 0) {
            float a = b_ih_d[r];
            #pragma unroll
            for (int k = 0; k < DI; ++k) a += wr[k] * fc4_b[k];
            b2[r] = a;
        }
    } else {
        int rr = r - 3 * DH;   // 0..15 (rows >= 12 zero-padded)
        int c0 = tid * 4;
        #pragma unroll
        for (int q = 0; q < 4; ++q)
            fc4bf[rr * DH + c0 + q] = (rr < DI) ? f2bf(fc4_w[rr * DH + c0 + q]) : (unsigned short)0;
    }
}

// ---------------- encoder: persistent GRU (3 syncs/step, release-flag barrier) ----------------
__global__ __launch_bounds__(384, 2)
void enc_kernel(const float* __restrict__ x, const float* __restrict__ w_ih,
                const float* __restrict__ w_hh, const float* __restrict__ b_ih,
                const float* __restrict__ b_hh, unsigned* __restrict__ hpp,
                float* __restrict__ hencF, unsigned* __restrict__ flags)
{
    const int tid = threadIdx.x;
    const int bid = blockIdx.x;
    const int bg = bid & 7;          // batch group
    const int cb = bid >> 3;         // unit slice
    const int growbase = bg * 32;
    const int ub = cb * 16;
    const int wave = tid >> 6, lane = tid & 63;
    const int rt = wave / 3, g = wave % 3;
    const int lrow = lane & 15, lk = lane >> 4;
    unsigned* flg = flags + bg * 64;

    __shared__ unsigned short hbuf[32 * DH];
    __shared__ float xbuf[32][DI];
    __shared__ float RZ[2][2][16][16];

    const int grow = g * DH + ub + lrow;
    const float bhh_l = b_hh[grow];
    const float bih_l = b_ih[grow];
    float wihr[DI];
    #pragma unroll
    for (int k = 0; k < DI; ++k) wihr[k] = w_ih[grow * DI + k];

    for (int i = tid; i < 32 * DH / 2; i += 384) ((unsigned*)hbuf)[i] = 0u;  // h0 = 0
    { // x_0 -> LDS
        int r = tid / DI, c = tid % DI;
        xbuf[r][c] = x[(size_t)(growbase + r) * (DT * DI) + c];
    }

    bf16x8 bfr[16];  // W_hh slice, register-resident
    {
        const float* wr = w_hh + (size_t)grow * DH;
        #pragma unroll
        for (int kk = 0; kk < 16; ++kk) {
            const float* p = wr + kk * 32 + lk * 8;
            bf16x8 v;
            #pragma unroll
            for (int j = 0; j < 8; ++j) v[j] = (__bf16)p[j];
            bfr[kk] = v;
        }
    }
    float hreg[4] = {0.f, 0.f, 0.f, 0.f};   // h state (g==2 waves)
    const int pid = (g != 2) ? ((rt * 2 + g) * 64 + lane) : 0;
    __syncthreads();

    for (int t = 0; t < DT; ++t) {
        const bool lastt = (t == DT - 1);
        // ---- A: gh MFMA + in-register gi + gates (+ x prefetch issue) ----
        f32x4 acc = mfma_hbuf(hbuf, bfr, rt * 16 + lrow, lk);
        float gi[4];
        #pragma unroll
        for (int i = 0; i < 4; ++i) {
            int row = rt * 16 + lk * 4 + i;
            float a2 = bih_l;
            #pragma unroll
            for (int k = 0; k < DI; ++k) a2 += xbuf[row][k] * wihr[k];
            gi[i] = a2;
        }
        float hn[4], gin[4];
        if (g == 0) {
            #pragma unroll
            for (int i = 0; i < 4; ++i)
                RZ[0][rt][lk * 4 + i][lrow] = sigm(acc[i] + bhh_l + gi[i]);
        } else if (g == 1) {
            #pragma unroll
            for (int i = 0; i < 4; ++i)
                RZ[1][rt][lk * 4 + i][lrow] = sigm(acc[i] + bhh_l + gi[i]);
        } else {
            #pragma unroll
            for (int i = 0; i < 4; ++i) { hn[i] = acc[i] + bhh_l; gin[i] = gi[i]; }
        }
        float xr0 = 0.f, xr1 = 0.f;
        if (g != 2 && !lastt) {
            xr0 = x[(size_t)(growbase + pid / 12) * (DT * DI) + (size_t)(t + 1) * DI + pid % 12];
            if (pid < 128) {
                int e = 256 + pid;
                xr1 = x[(size_t)(growbase + e / 12) * (DT * DI) + (size_t)(t + 1) * DI + e % 12];
            }
        }
        __syncthreads();
        // ---- C: combine + publish + per-wave RELEASE flag (g2) || poll (wave 1) ----
        if (g == 2) {
            if (!lastt) {
                unsigned* dst = hpp + ((t + 1) & 1) * (DB * DH / 2);
                #pragma unroll
                for (int i = 0; i < 4; ++i) {
                    int ri = lk * 4 + i;
                    int row = rt * 16 + ri;
                    float r = RZ[0][rt][ri][lrow];
                    float z = RZ[1][rt][ri][lrow];
                    float n = tanh_f(gin[i] + r * hn[i]);
                    hreg[i] = (1.f - z) * n + z * hreg[i];
                    float hp = __shfl_xor(hreg[i], 1);
                    if (!(lrow & 1)) {
                        unsigned val = (unsigned)f2bf(hreg[i]) | ((unsigned)f2bf(hp) << 16);
                        __hip_atomic_store(dst + (unsigned)(growbase + row) * 256u +
                                           (unsigned)(cb * 8 + (lrow >> 1)),
                                           val, __ATOMIC_RELAXED, SCOPE);
                    }
                }
                if (lane == 0)
                    __hip_atomic_store(flg + (cb * 2 + rt), (unsigned)(t + 1),
                                       __ATOMIC_RELEASE, SCOPE);
            } else {
                #pragma unroll
                for (int i = 0; i < 4; ++i) {
                    int row = rt * 16 + lk * 4 + i;
                    float r = RZ[0][rt][lk * 4 + i][lrow];
                    float z = RZ[1][rt][lk * 4 + i][lrow];
                    float n = tanh_f(gin[i] + r * hn[i]);
                    hreg[i] = (1.f - z) * n + z * hreg[i];
                    hencF[(size_t)(growbase + row) * DH + ub + lrow] = hreg[i];
                }
            }
        }
        if (lastt) break;
        if (wave == 1) poll64(flg, lane, (unsigned)(t + 1));
        __syncthreads();
        // ---- stage h_{t+1} + commit x prefetch ----
        stage_h(hbuf, (const unsigned long long*)(hpp + ((t + 1) & 1) * (DB * DH / 2)) +
                      (size_t)growbase * 128, tid);
        if (g != 2) {
            xbuf[pid / 12][pid % 12] = xr0;
            if (pid < 128) { int e = 256 + pid; xbuf[e / 12][e % 12] = xr1; }
        }
        __syncthreads();
    }
}

// ---------------- latent head + decoder init ----------------
__global__ void mid_kernel(const float* __restrict__ henc, const float* __restrict__ eps,
                           const float* __restrict__ fc1_w, const float* __restrict__ fc1_b,
                           const float* __restrict__ fc11_w, const float* __restrict__ fc11_b,
                           const float* __restrict__ fc12_w, const float* __restrict__ fc12_b,
                           const float* __restrict__ fc2_w, const float* __restrict__ fc2_b,
                           const float* __restrict__ fc3_w, const float* __restrict__ fc3_b,
                           float* __restrict__ hdecF, unsigned* __restrict__ hppD0,
                           float* __restrict__ out)
{
    const int row = blockIdx.x, tid = threadIdx.x;  // 256 threads
    __shared__ float v0[512], v1[256], zb[64], ubuf[256];
    for (int k = tid; k < 512; k += 256) v0[k] = lrelu(henc[(size_t)row * 512 + k]);
    __syncthreads();
    {
        float a = fc1_b[tid];
        const float* w = fc1_w + (size_t)tid * 512;
        for (int k = 0; k < 512; k += 4) {
            float4 wv = *(const float4*)(w + k);
            a += wv.x * v0[k] + wv.y * v0[k + 1] + wv.z * v0[k + 2] + wv.w * v0[k + 3];
        }
        v1[tid] = lrelu(a);
    }
    __syncthreads();
    if (tid < 64) {
        float m = fc11_b[tid], lv = fc12_b[tid];
        const float* w1 = fc11_w + (size_t)tid * 256;
        const float* w2 = fc12_w + (size_t)tid * 256;
        for (int k = 0; k < 256; k += 4) {
            float4 a = *(const float4*)(w1 + k);
            float4 b = *(const float4*)(w2 + k);
            m  += a.x * v1[k] + a.y * v1[k + 1] + a.z * v1[k + 2] + a.w * v1[k + 3];
            lv += b.x * v1[k] + b.y * v1[k + 1] + b.z * v1[k + 2] + b.w * v1[k + 3];
        }
        out[786432 + row * 64 + tid] = m;
        out[802816 + row * 64 + tid] = lv;
        zb[tid] = m + __expf(0.5f * lv) * eps[row * 64 + tid];
    }
    __syncthreads();
    {
        float a = fc2_b[tid];
        const float* w = fc2_w + (size_t)tid * 64;
        for (int k = 0; k < 64; k += 4) {
            float4 wv = *(const float4*)(w + k);
            a += wv.x * zb[k] + wv.y * zb[k + 1] + wv.z * zb[k + 2] + wv.w * zb[k + 3];
        }
        ubuf[tid] = lrelu(a);
    }
    __syncthreads();
    {
        float hv[2];
        #pragma unroll
        for (int q = 0; q < 2; ++q) {
            int j = 2 * tid + q;
            float a = fc3_b[j];
            const float* w = fc3_w + (size_t)j * 256;
            for (int k = 0; k < 256; k += 4) {
                float4 wv = *(const float4*)(w + k);
                a += wv.x * ubuf[k] + wv.y * ubuf[k + 1] + wv.z * ubuf[k + 2] + wv.w * ubuf[k + 3];
            }
            hdecF[(size_t)row * 512 + j] = a;
            hv[q] = a;
        }
        hppD0[row * 256 + tid] = (unsigned)f2bf(hv[0]) | ((unsigned)f2bf(hv[1]) << 16);
    }
}

// ---------------- decoder: persistent GRU, W2-folded, y in barrier shadow (3 syncs/step) ----------------
__global__ __launch_bounds__(384, 2)
void dec_kernel(const float* __restrict__ w_hh, const float* __restrict__ b_ih,
                const float* __restrict__ b_hh, const unsigned short* __restrict__ W2bf,
                const float* __restrict__ b2, const unsigned short* __restrict__ fc4bf,
                const float* __restrict__ fc4_b, const float* __restrict__ hdecF,
                unsigned* __restrict__ hpp, unsigned* __restrict__ flags,
                float* __restrict__ out)
{
    const int tid = threadIdx.x;
    const int bid = blockIdx.x;
    const int bg = bid & 7;
    const int cb = bid >> 3;
    const int growbase = bg * 32;
    const int ub = cb * 16;
    const int wave = tid >> 6, lane = tid & 63;
    const int rt = wave / 3, g = wave % 3;
    const int lrow = lane & 15, lk = lane >> 4;
    unsigned* flg = flags + bg * 64;

    __shared__ unsigned short hbuf[32 * DH];
    __shared__ float RZ[2][2][16][16];

    const int grow = g * DH + ub + lrow;
    const float bhh_l = b_hh[grow];
    const float bih_l = b_ih[grow];
    const float b2_l  = b2[grow];
    const float fb4_l = (lrow < DI) ? fc4_b[lrow] : 0.f;

    bf16x8 bfr[16];   // w_hh gate-slice
    {
        const float* wr = w_hh + (size_t)grow * DH;
        #pragma unroll
        for (int kk = 0; kk < 16; ++kk) {
            const float* p = wr + kk * 32 + lk * 8;
            bf16x8 v;
            #pragma unroll
            for (int j = 0; j < 8; ++j) v[j] = (__bf16)p[j];
            bfr[kk] = v;
        }
    }
    bf16x8 w2fr[16];  // W2 gate-slice (bf16, direct)
    {
        const unsigned short* wr = W2bf + (size_t)grow * DH;
        #pragma unroll
        for (int kk = 0; kk < 16; ++kk)
            w2fr[kk] = *reinterpret_cast<const bf16x8*>(wr + kk * 32 + lk * 8);
    }
    float hreg[4] = {0.f, 0.f, 0.f, 0.f};
    if (g == 2) {
        #pragma unroll
        for (int i = 0; i < 4; ++i)
            hreg[i] = hdecF[(size_t)(growbase + rt * 16 + lk * 4 + i) * DH + ub + lrow];
    }
    // prologue: stage h_dec
    stage_h(hbuf, (const unsigned long long*)hpp + (size_t)growbase * 128, tid);
    __syncthreads();

    const bool ywave = (g == 0) && (cb == 0);
    const unsigned short* fp = fc4bf + (size_t)lrow * DH;

    for (int t = 0; t < DT; ++t) {
        // ---- A: gh + gi2 dual MFMA + gates ----
        f32x4 acc1 = {0.f, 0.f, 0.f, 0.f};
        f32x4 acc2 = {0.f, 0.f, 0.f, 0.f};
        {
            const int arow = rt * 16 + lrow;
            const unsigned rbase = (unsigned)arow * 1024u;
            const unsigned swz = (unsigned)((arow & 7) << 4);
            const char* hb = (const char*)hbuf;
            if (t == 0) {
                #pragma unroll
                for (int kk = 0; kk < 16; ++kk) {
                    unsigned off = rbase + (((unsigned)(kk * 64 + lk * 16)) ^ swz);
                    bf16x8 a = *(const bf16x8*)(hb + off);
                    acc1 = __builtin_amdgcn_mfma_f32_16x16x32_bf16(a, bfr[kk], acc1, 0, 0, 0);
                }
            } else {
                #pragma unroll
                for (int kk = 0; kk < 16; ++kk) {
                    unsigned off = rbase + (((unsigned)(kk * 64 + lk * 16)) ^ swz);
                    bf16x8 a = *(const bf16x8*)(hb + off);
                    acc1 = __builtin_amdgcn_mfma_f32_16x16x32_bf16(a, bfr[kk], acc1, 0, 0, 0);
                    acc2 = __builtin_amdgcn_mfma_f32_16x16x32_bf16(a, w2fr[kk], acc2, 0, 0, 0);
                }
            }
        }
        const float bsel = (t == 0) ? bih_l : b2_l;
        float hn[4], gin[4];
        if (g == 0) {
            #pragma unroll
            for (int i = 0; i < 4; ++i)
                RZ[0][rt][lk * 4 + i][lrow] = sigm(acc1[i] + bhh_l + acc2[i] + bsel);
        } else if (g == 1) {
            #pragma unroll
            for (int i = 0; i < 4; ++i)
                RZ[1][rt][lk * 4 + i][lrow] = sigm(acc1[i] + bhh_l + acc2[i] + bsel);
        } else {
            #pragma unroll
            for (int i = 0; i < 4; ++i) { hn[i] = acc1[i] + bhh_l; gin[i] = acc2[i] + bsel; }
        }
        __syncthreads();
        // ---- C: g2 combine+publish+RELEASE flag || ywave y-MFMA+out || wave1 poll ----
        if (g == 2) {
            unsigned* dst = hpp + ((t + 1) & 1) * (DB * DH / 2);
            #pragma unroll
            for (int i = 0; i < 4; ++i) {
                int ri = lk * 4 + i;
                int row = rt * 16 + ri;
                float r = RZ[0][rt][ri][lrow];
                float z = RZ[1][rt][ri][lrow];
                float n = tanh_f(gin[i] + r * hn[i]);
                hreg[i] = (1.f - z) * n + z * hreg[i];
                float hp = __shfl_xor(hreg[i], 1);
                if (!(lrow & 1)) {
                    unsigned val = (unsigned)f2bf(hreg[i]) | ((unsigned)f2bf(hp) << 16);
                    __hip_atomic_store(dst + (unsigned)(growbase + row) * 256u +
                                       (unsigned)(cb * 8 + (lrow >> 1)),
                                       val, __ATOMIC_RELAXED, SCOPE);
                }
            }
            if (lane == 0)
                __hip_atomic_store(flg + (cb * 2 + rt), (unsigned)(t + 1),
                                   __ATOMIC_RELEASE, SCOPE);
        } else if (ywave && t > 0) {
            // y_{t-1} = fc4(h_t): hidden in the barrier-wait shadow (hbuf stable until stage)
            f32x4 ya = {0.f, 0.f, 0.f, 0.f};
            const int arow = rt * 16 + lrow;
            const unsigned rbase = (unsigned)arow * 1024u;
            const unsigned swz = (unsigned)((arow & 7) << 4);
            const char* hb = (const char*)hbuf;
            #pragma unroll
            for (int kk = 0; kk < 16; ++kk) {
                unsigned off = rbase + (((unsigned)(kk * 64 + lk * 16)) ^ swz);
                bf16x8 a = *(const bf16x8*)(hb + off);
                bf16x8 yb = *reinterpret_cast<const bf16x8*>(fp + kk * 32 + lk * 8);
                ya = __builtin_amdgcn_mfma_f32_16x16x32_bf16(a, yb, ya, 0, 0, 0);
            }
            if (lrow < DI) {
                #pragma unroll
                for (int i = 0; i < 4; ++i)
                    out[(size_t)(growbase + rt * 16 + lk * 4 + i) * (DT * DI) +
                        (size_t)(t - 1) * DI + lrow] = ya[i] + fb4_l;
            }
        }
        if (wave == 1) poll64(flg, lane, (unsigned)(t + 1));
        __syncthreads();
        stage_h(hbuf, (const unsigned long long*)(hpp + ((t + 1) & 1) * (DB * DH / 2)) +
                      (size_t)growbase * 128, tid);
        __syncthreads();
    }
    // epilogue: y_255 = fc4(h_256)
    if (ywave) {
        f32x4 ya = {0.f, 0.f, 0.f, 0.f};
        const int arow = rt * 16 + lrow;
        const unsigned rbase = (unsigned)arow * 1024u;
        const unsigned swz = (unsigned)((arow & 7) << 4);
        const char* hb = (const char*)hbuf;
        #pragma unroll
        for (int kk = 0; kk < 16; ++kk) {
            unsigned off = rbase + (((unsigned)(kk * 64 + lk * 16)) ^ swz);
            bf16x8 a = *(const bf16x8*)(hb + off);
            bf16x8 yb = *reinterpret_cast<const bf16x8*>(fp + kk * 32 + lk * 8);
            ya = __builtin_amdgcn_mfma_f32_16x16x32_bf16(a, yb, ya, 0, 0, 0);
        }
        if (lrow < DI) {
            #pragma unroll
            for (int i = 0; i < 4; ++i)
                out[(size_t)(growbase + rt * 16 + lk * 4 + i) * (DT * DI) +
                    (size_t)(DT - 1) * DI + lrow] = ya[i] + fb4_l;
        }
    }
}

extern "C" void kernel_launch(void* const* d_in, const int* in_sizes, int n_in,
                              void* d_out, int out_size, void* d_ws, size_t ws_size,
                              hipStream_t stream)
{
    const float* x      = (const float*)d_in[0];
    const float* eps    = (const float*)d_in[1];
    const float* w_ih_e = (const float*)d_in[2];
    const float* w_hh_e = (const float*)d_in[3];
    const float* b_ih_e = (const float*)d_in[4];
    const float* b_hh_e = (const float*)d_in[5];
    const float* w_ih_d = (const float*)d_in[6];
    const float* w_hh_d = (const float*)d_in[7];
    const float* b_ih_d = (const float*)d_in[8];
    const float* b_hh_d = (const float*)d_in[9];
    const float* fc1_w  = (const float*)d_in[10];
    const float* fc1_b  = (const float*)d_in[11];
    const float* fc11_w = (const float*)d_in[12];
    const float* fc11_b = (const float*)d_in[13];
    const float* fc12_w = (const float*)d_in[14];
    const float* fc12_b = (const float*)d_in[15];
    const float* fc2_w  = (const float*)d_in[16];
    const float* fc2_b  = (const float*)d_in[17];
    const float* fc3_w  = (const float*)d_in[18];
    const float* fc3_b  = (const float*)d_in[19];
    const float* fc4_w  = (const float*)d_in[20];
    const float* fc4_b  = (const float*)d_in[21];

    char* ws = (char*)d_ws;
    unsigned* hppE        = (unsigned*)(ws + 0);        // 2 x 256 x 512 bf16
    unsigned* hppD        = (unsigned*)(ws + 524288);   // 2 x 256 x 512 bf16
    float* hencF          = (float*)(ws + 1048576);     // 256 x 512 f32
    float* hdecF          = (float*)(ws + 1572864);     // 256 x 512 f32
    unsigned* flagE       = (unsigned*)(ws + 2097152);  // 8 groups x 64 flags
    unsigned* flagD       = (unsigned*)(ws + 2099200);
    unsigned short* W2bf  = (unsigned short*)(ws + 2101248);  // 1536 x 512 bf16
    float* b2             = (float*)(ws + 3674112);           // 1536 f32
    unsigned short* fc4bf = (unsigned short*)(ws + 3680256);  // 16 x 512 bf16 (zero-padded)
    float* out = (float*)d_out;

    init_kernel<<<4, 256, 0, stream>>>(flagE, flagD);
    prep_kernel<<<1552, 128, 0, stream>>>(w_ih_d, fc4_w, b_ih_d, fc4_b, W2bf, b2, fc4bf);
    enc_kernel<<<256, 384, 0, stream>>>(x, w_ih_e, w_hh_e, b_ih_e, b_hh_e, hppE, hencF, flagE);
    mid_kernel<<<256, 256, 0, stream>>>(hencF, eps, fc1_w, fc1_b, fc11_w, fc11_b,
                                        fc12_w, fc12_b, fc2_w, fc2_b, fc3_w, fc3_b,
                                        hdecF, hppD, out);
    dec_kernel<<<256, 384, 0, stream>>>(w_hh_d, b_ih_d, b_hh_d, W2bf, b2, fc4bf, fc4_b,
                                        hdecF, hppD, flagD, out);
}

// Round 14
// 2916.281 us; speedup vs baseline: 2.3733x; 2.3733x over previous
//
#include <hip/hip_runtime.h>
#include <hip/hip_bf16.h>

#define DI 12
#define DH 512
#define DT 256
#define DB 256
#define SCOPE __HIP_MEMORY_SCOPE_AGENT

typedef float f32x4 __attribute__((ext_vector_type(4)));
typedef __bf16 bf16x8 __attribute__((ext_vector_type(8)));

__device__ __forceinline__ float sigm(float x) { return 1.f / (1.f + __expf(-x)); }
__device__ __forceinline__ float tanh_f(float x) {
    float xc = fminf(fmaxf(x, -15.f), 15.f);
    float e = __expf(-2.f * xc);
    return (1.f - e) / (1.f + e);
}
__device__ __forceinline__ float lrelu(float x) { return x > 0.f ? x : 0.01f * x; }
__device__ __forceinline__ unsigned short f2bf(float f) {
    return __builtin_bit_cast(unsigned short, (__bf16)f);
}

// Parallel h staging: issue all L3 loads first (independent), then LDS-write.
__device__ __forceinline__ void stage_h(unsigned short* hbuf, const unsigned long long* src2, int tid) {
    unsigned long long tmp[11];
    #pragma unroll
    for (int j = 0; j < 11; ++j) {
        int i = tid + j * 384;
        if (i < 4096) tmp[j] = __hip_atomic_load(src2 + i, __ATOMIC_RELAXED, SCOPE);
    }
    #pragma unroll
    for (int j = 0; j < 11; ++j) {
        int i = tid + j * 384;
        if (i < 4096) {
            int row = i >> 7, dq = i & 127;
            unsigned off = (unsigned)row * 1024u + (((unsigned)(dq * 8)) ^ ((unsigned)((row & 7) << 4)));
            *(unsigned long long*)((char*)hbuf + off) = tmp[j];
        }
    }
}

// Poll 32 per-block flags (relaxed), then one acquire fence. NO release stores anywhere:
// publish stores are drained by the preceding __syncthreads (vmcnt(0) before s_barrier).
__device__ __forceinline__ void poll32(const unsigned* fl, int lane, unsigned gen) {
    while (true) {
        unsigned v = __hip_atomic_load(fl + (lane & 31), __ATOMIC_RELAXED, SCOPE);
        if (__all((int)(v >= gen))) break;
        __builtin_amdgcn_s_sleep(1);
    }
    __builtin_amdgcn_fence(__ATOMIC_ACQUIRE, "agent");
}

__device__ __forceinline__ f32x4 mfma_hbuf(const unsigned short* hbuf, const bf16x8* bw,
                                           int arow, int lk) {
    f32x4 acc = {0.f, 0.f, 0.f, 0.f};
    const unsigned rbase = (unsigned)arow * 1024u;
    const unsigned swz = (unsigned)((arow & 7) << 4);
    const char* hb = (const char*)hbuf;
    #pragma unroll
    for (int kk = 0; kk < 16; ++kk) {
        unsigned off = rbase + (((unsigned)(kk * 64 + lk * 16)) ^ swz);
        bf16x8 a = *(const bf16x8*)(hb + off);
        acc = __builtin_amdgcn_mfma_f32_16x16x32_bf16(a, bw[kk], acc, 0, 0, 0);
    }
    return acc;
}

// ---------------- init: zero generation flags ----------------
__global__ void init_kernel(unsigned* flE, unsigned* flD) {
    if (blockIdx.x == 0) flE[threadIdx.x] = 0u;
    else flD[threadIdx.x] = 0u;
}

// ---------------- prep: W2 = w_ih_d @ fc4_w (bf16), b2 = b_ih_d + w_ih_d@fc4_b, fc4 -> bf16 ----
__global__ void prep_kernel(const float* __restrict__ w_ih_d, const float* __restrict__ fc4_w,
                            const float* __restrict__ b_ih_d, const float* __restrict__ fc4_b,
                            unsigned short* __restrict__ W2bf, float* __restrict__ b2,
                            unsigned short* __restrict__ fc4bf)
{
    const int r = blockIdx.x, tid = threadIdx.x;   // 1552 blocks x 128 threads
    if (r < 3 * DH) {
        float wr[DI];
        #pragma unroll
        for (int k = 0; k < DI; ++k) wr[k] = w_ih_d[r * DI + k];
        int c0 = tid * 4;
        #pragma unroll
        for (int q = 0; q < 4; ++q) {
            int c = c0 + q;
            float a = 0.f;
            #pragma unroll
            for (int k = 0; k < DI; ++k) a += wr[k] * fc4_w[k * DH + c];
            W2bf[(size_t)r * DH + c] = f2bf(a);
        }
        if (tid == 0) {
            float a = b_ih_d[r];
            #pragma unroll
            for (int k = 0; k < DI; ++k) a += wr[k] * fc4_b[k];
            b2[r] = a;
        }
    } else {
        int rr = r - 3 * DH;   // 0..15 (rows >= 12 zero-padded)
        int c0 = tid * 4;
        #pragma unroll
        for (int q = 0; q < 4; ++q)
            fc4bf[rr * DH + c0 + q] = (rr < DI) ? f2bf(fc4_w[rr * DH + c0 + q]) : (unsigned short)0;
    }
}

// ---------------- encoder: persistent GRU (drained-relaxed-flag barrier; proven protocol) ----------------
__global__ __launch_bounds__(384, 2)
void enc_kernel(const float* __restrict__ x, const float* __restrict__ w_ih,
                const float* __restrict__ w_hh, const float* __restrict__ b_ih,
                const float* __restrict__ b_hh, unsigned* __restrict__ hpp,
                float* __restrict__ hencF, unsigned* __restrict__ flags)
{
    const int tid = threadIdx.x;
    const int bid = blockIdx.x;
    const int bg = bid & 7;          // batch group
    const int cb = bid >> 3;         // unit slice
    const int growbase = bg * 32;
    const int ub = cb * 16;
    const int wave = tid >> 6, lane = tid & 63;
    const int rt = wave / 3, g = wave % 3;
    const int lrow = lane & 15, lk = lane >> 4;
    unsigned* flg = flags + bg * 32;

    __shared__ unsigned short hbuf[32 * DH];
    __shared__ float xbuf[32][DI];
    __shared__ float RZ[2][2][16][16];

    const int grow = g * DH + ub + lrow;
    const float bhh_l = b_hh[grow];
    const float bih_l = b_ih[grow];
    float wihr[DI];
    #pragma unroll
    for (int k = 0; k < DI; ++k) wihr[k] = w_ih[grow * DI + k];

    for (int i = tid; i < 32 * DH / 2; i += 384) ((unsigned*)hbuf)[i] = 0u;  // h0 = 0
    { // x_0 -> LDS
        int r = tid / DI, c = tid % DI;
        xbuf[r][c] = x[(size_t)(growbase + r) * (DT * DI) + c];
    }

    bf16x8 bfr[16];  // W_hh slice, register-resident
    {
        const float* wr = w_hh + (size_t)grow * DH;
        #pragma unroll
        for (int kk = 0; kk < 16; ++kk) {
            const float* p = wr + kk * 32 + lk * 8;
            bf16x8 v;
            #pragma unroll
            for (int j = 0; j < 8; ++j) v[j] = (__bf16)p[j];
            bfr[kk] = v;
        }
    }
    float hreg[4] = {0.f, 0.f, 0.f, 0.f};   // h state (g==2 waves)
    const int pid = (g != 2) ? ((rt * 2 + g) * 64 + lane) : 0;
    __syncthreads();

    for (int t = 0; t < DT; ++t) {
        const bool lastt = (t == DT - 1);
        // ---- A: gh MFMA + in-register gi + gates (+ x prefetch issue) ----
        f32x4 acc = mfma_hbuf(hbuf, bfr, rt * 16 + lrow, lk);
        float gi[4];
        #pragma unroll
        for (int i = 0; i < 4; ++i) {
            int row = rt * 16 + lk * 4 + i;
            float a2 = bih_l;
            #pragma unroll
            for (int k = 0; k < DI; ++k) a2 += xbuf[row][k] * wihr[k];
            gi[i] = a2;
        }
        float hn[4], gin[4];
        if (g == 0) {
            #pragma unroll
            for (int i = 0; i < 4; ++i)
                RZ[0][rt][lk * 4 + i][lrow] = sigm(acc[i] + bhh_l + gi[i]);
        } else if (g == 1) {
            #pragma unroll
            for (int i = 0; i < 4; ++i)
                RZ[1][rt][lk * 4 + i][lrow] = sigm(acc[i] + bhh_l + gi[i]);
        } else {
            #pragma unroll
            for (int i = 0; i < 4; ++i) { hn[i] = acc[i] + bhh_l; gin[i] = gi[i]; }
        }
        float xr0 = 0.f, xr1 = 0.f;
        if (g != 2 && !lastt) {
            xr0 = x[(size_t)(growbase + pid / 12) * (DT * DI) + (size_t)(t + 1) * DI + pid % 12];
            if (pid < 128) {
                int e = 256 + pid;
                xr1 = x[(size_t)(growbase + e / 12) * (DT * DI) + (size_t)(t + 1) * DI + e % 12];
            }
        }
        __syncthreads();
        // ---- C: combine (g2) + publish (relaxed stores only) ----
        if (g == 2) {
            if (!lastt) {
                unsigned* dst = hpp + ((t + 1) & 1) * (DB * DH / 2);
                #pragma unroll
                for (int i = 0; i < 4; ++i) {
                    int ri = lk * 4 + i;
                    int row = rt * 16 + ri;
                    float r = RZ[0][rt][ri][lrow];
                    float z = RZ[1][rt][ri][lrow];
                    float n = tanh_f(gin[i] + r * hn[i]);
                    hreg[i] = (1.f - z) * n + z * hreg[i];
                    float hp = __shfl_xor(hreg[i], 1);
                    if (!(lrow & 1)) {
                        unsigned val = (unsigned)f2bf(hreg[i]) | ((unsigned)f2bf(hp) << 16);
                        __hip_atomic_store(dst + (unsigned)(growbase + row) * 256u +
                                           (unsigned)(cb * 8 + (lrow >> 1)),
                                           val, __ATOMIC_RELAXED, SCOPE);
                    }
                }
            } else {
                #pragma unroll
                for (int i = 0; i < 4; ++i) {
                    int row = rt * 16 + lk * 4 + i;
                    float r = RZ[0][rt][lk * 4 + i][lrow];
                    float z = RZ[1][rt][lk * 4 + i][lrow];
                    float n = tanh_f(gin[i] + r * hn[i]);
                    hreg[i] = (1.f - z) * n + z * hreg[i];
                    hencF[(size_t)(growbase + row) * DH + ub + lrow] = hreg[i];
                }
            }
        }
        if (lastt) break;
        __syncthreads();   // drains publish stores (vmcnt(0) before s_barrier)
        const unsigned gen = (unsigned)(t + 1);
        if (tid == 0) __hip_atomic_store(flg + cb, gen, __ATOMIC_RELAXED, SCOPE);
        if (wave == 0) poll32(flg, lane, gen);
        __syncthreads();
        // ---- stage h_{t+1} + commit x prefetch ----
        stage_h(hbuf, (const unsigned long long*)(hpp + ((t + 1) & 1) * (DB * DH / 2)) +
                      (size_t)growbase * 128, tid);
        if (g != 2) {
            xbuf[pid / 12][pid % 12] = xr0;
            if (pid < 128) { int e = 256 + pid; xbuf[e / 12][e % 12] = xr1; }
        }
        __syncthreads();
    }
}

// ---------------- latent head + decoder init ----------------
__global__ void mid_kernel(const float* __restrict__ henc, const float* __restrict__ eps,
                           const float* __restrict__ fc1_w, const float* __restrict__ fc1_b,
                           const float* __restrict__ fc11_w, const float* __restrict__ fc11_b,
                           const float* __restrict__ fc12_w, const float* __restrict__ fc12_b,
                           const float* __restrict__ fc2_w, const float* __restrict__ fc2_b,
                           const float* __restrict__ fc3_w, const float* __restrict__ fc3_b,
                           float* __restrict__ hdecF, unsigned* __restrict__ hppD0,
                           float* __restrict__ out)
{
    const int row = blockIdx.x, tid = threadIdx.x;  // 256 threads
    __shared__ float v0[512], v1[256], zb[64], ubuf[256];
    for (int k = tid; k < 512; k += 256) v0[k] = lrelu(henc[(size_t)row * 512 + k]);
    __syncthreads();
    {
        float a = fc1_b[tid];
        const float* w = fc1_w + (size_t)tid * 512;
        for (int k = 0; k < 512; k += 4) {
            float4 wv = *(const float4*)(w + k);
            a += wv.x * v0[k] + wv.y * v0[k + 1] + wv.z * v0[k + 2] + wv.w * v0[k + 3];
        }
        v1[tid] = lrelu(a);
    }
    __syncthreads();
    if (tid < 64) {
        float m = fc11_b[tid], lv = fc12_b[tid];
        const float* w1 = fc11_w + (size_t)tid * 256;
        const float* w2 = fc12_w + (size_t)tid * 256;
        for (int k = 0; k < 256; k += 4) {
            float4 a = *(const float4*)(w1 + k);
            float4 b = *(const float4*)(w2 + k);
            m  += a.x * v1[k] + a.y * v1[k + 1] + a.z * v1[k + 2] + a.w * v1[k + 3];
            lv += b.x * v1[k] + b.y * v1[k + 1] + b.z * v1[k + 2] + b.w * v1[k + 3];
        }
        out[786432 + row * 64 + tid] = m;
        out[802816 + row * 64 + tid] = lv;
        zb[tid] = m + __expf(0.5f * lv) * eps[row * 64 + tid];
    }
    __syncthreads();
    {
        float a = fc2_b[tid];
        const float* w = fc2_w + (size_t)tid * 64;
        for (int k = 0; k < 64; k += 4) {
            float4 wv = *(const float4*)(w + k);
            a += wv.x * zb[k] + wv.y * zb[k + 1] + wv.z * zb[k + 2] + wv.w * zb[k + 3];
        }
        ubuf[tid] = lrelu(a);
    }
    __syncthreads();
    {
        float hv[2];
        #pragma unroll
        for (int q = 0; q < 2; ++q) {
            int j = 2 * tid + q;
            float a = fc3_b[j];
            const float* w = fc3_w + (size_t)j * 256;
            for (int k = 0; k < 256; k += 4) {
                float4 wv = *(const float4*)(w + k);
                a += wv.x * ubuf[k] + wv.y * ubuf[k + 1] + wv.z * ubuf[k + 2] + wv.w * ubuf[k + 3];
            }
            hdecF[(size_t)row * 512 + j] = a;
            hv[q] = a;
        }
        hppD0[row * 256 + tid] = (unsigned)f2bf(hv[0]) | ((unsigned)f2bf(hv[1]) << 16);
    }
}

// ---------------- decoder: W2-folded GRU; y-MFMA in the poll shadow; drained-relaxed-flag barrier ----------------
__global__ __launch_bounds__(384, 2)
void dec_kernel(const float* __restrict__ w_hh, const float* __restrict__ b_ih,
                const float* __restrict__ b_hh, const unsigned short* __restrict__ W2bf,
                const float* __restrict__ b2, const unsigned short* __restrict__ fc4bf,
                const float* __restrict__ fc4_b, const float* __restrict__ hdecF,
                unsigned* __restrict__ hpp, unsigned* __restrict__ flags,
                float* __restrict__ out)
{
    const int tid = threadIdx.x;
    const int bid = blockIdx.x;
    const int bg = bid & 7;
    const int cb = bid >> 3;
    const int growbase = bg * 32;
    const int ub = cb * 16;
    const int wave = tid >> 6, lane = tid & 63;
    const int rt = wave / 3, g = wave % 3;
    const int lrow = lane & 15, lk = lane >> 4;
    unsigned* flg = flags + bg * 32;

    __shared__ unsigned short hbuf[32 * DH];
    __shared__ float RZ[2][2][16][16];

    const int grow = g * DH + ub + lrow;
    const float bhh_l = b_hh[grow];
    const float bih_l = b_ih[grow];
    const float b2_l  = b2[grow];
    const float fb4_l = (lrow < DI) ? fc4_b[lrow] : 0.f;

    bf16x8 bfr[16];   // w_hh gate-slice
    {
        const float* wr = w_hh + (size_t)grow * DH;
        #pragma unroll
        for (int kk = 0; kk < 16; ++kk) {
            const float* p = wr + kk * 32 + lk * 8;
            bf16x8 v;
            #pragma unroll
            for (int j = 0; j < 8; ++j) v[j] = (__bf16)p[j];
            bfr[kk] = v;
        }
    }
    bf16x8 w2fr[16];  // W2 gate-slice (bf16, direct)
    {
        const unsigned short* wr = W2bf + (size_t)grow * DH;
        #pragma unroll
        for (int kk = 0; kk < 16; ++kk)
            w2fr[kk] = *reinterpret_cast<const bf16x8*>(wr + kk * 32 + lk * 8);
    }
    float hreg[4] = {0.f, 0.f, 0.f, 0.f};
    if (g == 2) {
        #pragma unroll
        for (int i = 0; i < 4; ++i)
            hreg[i] = hdecF[(size_t)(growbase + rt * 16 + lk * 4 + i) * DH + ub + lrow];
    }
    // prologue: stage h_dec
    stage_h(hbuf, (const unsigned long long*)hpp + (size_t)growbase * 128, tid);
    __syncthreads();

    const bool ywave = (g == 0) && (cb == 0);   // waves 0 and 3 of cb==0 blocks
    const unsigned short* fp = fc4bf + (size_t)lrow * DH;

    for (int t = 0; t < DT; ++t) {
        // ---- A: gh + gi2 dual MFMA + gates ----
        f32x4 acc1 = {0.f, 0.f, 0.f, 0.f};
        f32x4 acc2 = {0.f, 0.f, 0.f, 0.f};
        {
            const int arow = rt * 16 + lrow;
            const unsigned rbase = (unsigned)arow * 1024u;
            const unsigned swz = (unsigned)((arow & 7) << 4);
            const char* hb = (const char*)hbuf;
            if (t == 0) {
                #pragma unroll
                for (int kk = 0; kk < 16; ++kk) {
                    unsigned off = rbase + (((unsigned)(kk * 64 + lk * 16)) ^ swz);
                    bf16x8 a = *(const bf16x8*)(hb + off);
                    acc1 = __builtin_amdgcn_mfma_f32_16x16x32_bf16(a, bfr[kk], acc1, 0, 0, 0);
                }
            } else {
                #pragma unroll
                for (int kk = 0; kk < 16; ++kk) {
                    unsigned off = rbase + (((unsigned)(kk * 64 + lk * 16)) ^ swz);
                    bf16x8 a = *(const bf16x8*)(hb + off);
                    acc1 = __builtin_amdgcn_mfma_f32_16x16x32_bf16(a, bfr[kk], acc1, 0, 0, 0);
                    acc2 = __builtin_amdgcn_mfma_f32_16x16x32_bf16(a, w2fr[kk], acc2, 0, 0, 0);
                }
            }
        }
        const float bsel = (t == 0) ? bih_l : b2_l;
        float hn[4], gin[4];
        if (g == 0) {
            #pragma unroll
            for (int i = 0; i < 4; ++i)
                RZ[0][rt][lk * 4 + i][lrow] = sigm(acc1[i] + bhh_l + acc2[i] + bsel);
        } else if (g == 1) {
            #pragma unroll
            for (int i = 0; i < 4; ++i)
                RZ[1][rt][lk * 4 + i][lrow] = sigm(acc1[i] + bhh_l + acc2[i] + bsel);
        } else {
            #pragma unroll
            for (int i = 0; i < 4; ++i) { hn[i] = acc1[i] + bhh_l; gin[i] = acc2[i] + bsel; }
        }
        __syncthreads();
        // ---- C: g2 combine + publish (relaxed stores; every step — epilogue needs h_256) ----
        if (g == 2) {
            unsigned* dst = hpp + ((t + 1) & 1) * (DB * DH / 2);
            #pragma unroll
            for (int i = 0; i < 4; ++i) {
                int ri = lk * 4 + i;
                int row = rt * 16 + ri;
                float r = RZ[0][rt][ri][lrow];
                float z = RZ[1][rt][ri][lrow];
                float n = tanh_f(gin[i] + r * hn[i]);
                hreg[i] = (1.f - z) * n + z * hreg[i];
                float hp = __shfl_xor(hreg[i], 1);
                if (!(lrow & 1)) {
                    unsigned val = (unsigned)f2bf(hreg[i]) | ((unsigned)f2bf(hp) << 16);
                    __hip_atomic_store(dst + (unsigned)(growbase + row) * 256u +
                                       (unsigned)(cb * 8 + (lrow >> 1)),
                                       val, __ATOMIC_RELAXED, SCOPE);
                }
            }
        }
        __syncthreads();   // drains publish stores (vmcnt(0) before s_barrier)
        const unsigned gen = (unsigned)(t + 1);
        if (tid == 0) __hip_atomic_store(flg + cb, gen, __ATOMIC_RELAXED, SCOPE);
        if (wave == 1) {
            poll32(flg, lane, gen);
        } else if (ywave && t > 0) {
            // y_{t-1} = fc4(h_t) in the poll shadow (hbuf stable until stage)
            f32x4 ya = {0.f, 0.f, 0.f, 0.f};
            const int arow = rt * 16 + lrow;
            const unsigned rbase = (unsigned)arow * 1024u;
            const unsigned swz = (unsigned)((arow & 7) << 4);
            const char* hb = (const char*)hbuf;
            #pragma unroll
            for (int kk = 0; kk < 16; ++kk) {
                unsigned off = rbase + (((unsigned)(kk * 64 + lk * 16)) ^ swz);
                bf16x8 a = *(const bf16x8*)(hb + off);
                bf16x8 yb = *reinterpret_cast<const bf16x8*>(fp + kk * 32 + lk * 8);
                ya = __builtin_amdgcn_mfma_f32_16x16x32_bf16(a, yb, ya, 0, 0, 0);
            }
            if (lrow < DI) {
                #pragma unroll
                for (int i = 0; i < 4; ++i)
                    out[(size_t)(growbase + rt * 16 + lk * 4 + i) * (DT * DI) +
                        (size_t)(t - 1) * DI + lrow] = ya[i] + fb4_l;
            }
        }
        __syncthreads();
        stage_h(hbuf, (const unsigned long long*)(hpp + ((t + 1) & 1) * (DB * DH / 2)) +
                      (size_t)growbase * 128, tid);
        __syncthreads();
    }
    // epilogue: y_255 = fc4(h_256)
    if (ywave) {
        f32x4 ya = {0.f, 0.f, 0.f, 0.f};
        const int arow = rt * 16 + lrow;
        const unsigned rbase = (unsigned)arow * 1024u;
        const unsigned swz = (unsigned)((arow & 7) << 4);
        const char* hb = (const char*)hbuf;
        #pragma unroll
        for (int kk = 0; kk < 16; ++kk) {
            unsigned off = rbase + (((unsigned)(kk * 64 + lk * 16)) ^ swz);
            bf16x8 a = *(const bf16x8*)(hb + off);
            bf16x8 yb = *reinterpret_cast<const bf16x8*>(fp + kk * 32 + lk * 8);
            ya = __builtin_amdgcn_mfma_f32_16x16x32_bf16(a, yb, ya, 0, 0, 0);
        }
        if (lrow < DI) {
            #pragma unroll
            for (int i = 0; i < 4; ++i)
                out[(size_t)(growbase + rt * 16 + lk * 4 + i) * (DT * DI) +
                    (size_t)(DT - 1) * DI + lrow] = ya[i] + fb4_l;
        }
    }
}

extern "C" void kernel_launch(void* const* d_in, const int* in_sizes, int n_in,
                              void* d_out, int out_size, void* d_ws, size_t ws_size,
                              hipStream_t stream)
{
    const float* x      = (const float*)d_in[0];
    const float* eps    = (const float*)d_in[1];
    const float* w_ih_e = (const float*)d_in[2];
    const float* w_hh_e = (const float*)d_in[3];
    const float* b_ih_e = (const float*)d_in[4];
    const float* b_hh_e = (const float*)d_in[5];
    const float* w_ih_d = (const float*)d_in[6];
    const float* w_hh_d = (const float*)d_in[7];
    const float* b_ih_d = (const float*)d_in[8];
    const float* b_hh_d = (const float*)d_in[9];
    const float* fc1_w  = (const float*)d_in[10];
    const float* fc1_b  = (const float*)d_in[11];
    const float* fc11_w = (const float*)d_in[12];
    const float* fc11_b = (const float*)d_in[13];
    const float* fc12_w = (const float*)d_in[14];
    const float* fc12_b = (const float*)d_in[15];
    const float* fc2_w  = (const float*)d_in[16];
    const float* fc2_b  = (const float*)d_in[17];
    const float* fc3_w  = (const float*)d_in[18];
    const float* fc3_b  = (const float*)d_in[19];
    const float* fc4_w  = (const float*)d_in[20];
    const float* fc4_b  = (const float*)d_in[21];

    char* ws = (char*)d_ws;
    unsigned* hppE        = (unsigned*)(ws + 0);        // 2 x 256 x 512 bf16
    unsigned* hppD        = (unsigned*)(ws + 524288);   // 2 x 256 x 512 bf16
    float* hencF          = (float*)(ws + 1048576);     // 256 x 512 f32
    float* hdecF          = (float*)(ws + 1572864);     // 256 x 512 f32
    unsigned* flagE       = (unsigned*)(ws + 2097152);  // 8 groups x 32 slice flags
    unsigned* flagD       = (unsigned*)(ws + 2101248);
    unsigned short* W2bf  = (unsigned short*)(ws + 2105344);  // 1536 x 512 bf16
    float* b2             = (float*)(ws + 3678208);           // 1536 f32
    unsigned short* fc4bf = (unsigned short*)(ws + 3684352);  // 16 x 512 bf16 (zero-padded)
    float* out = (float*)d_out;

    init_kernel<<<2, 256, 0, stream>>>(flagE, flagD);
    prep_kernel<<<1552, 128, 0, stream>>>(w_ih_d, fc4_w, b_ih_d, fc4_b, W2bf, b2, fc4bf);
    enc_kernel<<<256, 384, 0, stream>>>(x, w_ih_e, w_hh_e, b_ih_e, b_hh_e, hppE, hencF, flagE);
    mid_kernel<<<256, 256, 0, stream>>>(hencF, eps, fc1_w, fc1_b, fc11_w, fc11_b,
                                        fc12_w, fc12_b, fc2_w, fc2_b, fc3_w, fc3_b,
                                        hdecF, hppD, out);
    dec_kernel<<<256, 384, 0, stream>>>(w_hh_d, b_ih_d, b_hh_d, W2bf, b2, fc4bf, fc4_b,
                                        hdecF, hppD, flagD, out);
}